// Round 4
// baseline (2859.779 us; speedup 1.0000x reference)
//
#include <hip/hip_runtime.h>
#include <hip/hip_bf16.h>

// AttentiveFuturecaster R3b: two kernels (R3 with nontemporal-store fix).
//  - af_encoder: 128 blocks x 1024 thr, BT=16. GRU recurrence, h carried as
//    bf16 hi+lo pairs in single-buffered LDS (2 barriers/step). Weights
//    streamed from L2 (bf16 blob in ws). hs stored nontemporal (u64).
//  - af_decoder: 256 blocks x 512 thr, BT=8. A/C rank-1 attention tables
//    computed once via MFMA from hs, then 32 steps: softmax -> ctx (VALU
//    stream of hs) -> GRU (MFMA) -> fc1 (MFMA) -> fc2 (dot).
// ws: [0,128MB) hs bf16 [B,T,H]; then 1MB bf16 weight blob (eWih,eWhh,dWhh,f1W).

#define B_    2048
#define T_    128
#define F_    64
#define H_    256
#define OUT_  32
#define BTE_  16
#define BTD_  8
#define NBE_  (B_ / BTE_)   // 128
#define NBD_  (B_ / BTD_)   // 256
#define HSTR_ 264
#define XSTR_ 72

#define W_EIH_  0
#define W_EHH_  (W_EIH_ + 3 * H_ * F_)
#define W_DHH_  (W_EHH_ + 3 * H_ * H_)
#define W_F1_   (W_DHH_ + 3 * H_ * H_)
#define W_TOT_  (W_F1_ + H_ * H_)

typedef __attribute__((ext_vector_type(8))) short bf16x8;
typedef __attribute__((ext_vector_type(4))) float f32x4;

__device__ __forceinline__ f32x4 mfma16(bf16x8 a, bf16x8 b, f32x4 c) {
  return __builtin_amdgcn_mfma_f32_16x16x32_bf16(a, b, c, 0, 0, 0);
}
__device__ __forceinline__ float sigm_(float x) { return 1.0f / (1.0f + __expf(-x)); }
__device__ __forceinline__ float tanh_(float x) {
  x = fminf(15.0f, fmaxf(-15.0f, x));
  float e = __expf(2.0f * x);
  return (e - 1.0f) / (e + 1.0f);
}
__device__ __forceinline__ unsigned short f2bf_(float f) {
  unsigned u = __float_as_uint(f);
  return (unsigned short)((u + 0x7FFFu + ((u >> 16) & 1u)) >> 16);
}
__device__ __forceinline__ float bf2f_(unsigned short s) {
  return __uint_as_float(((unsigned)s) << 16);
}

__global__ __launch_bounds__(256) void af_convert_weights(
    const float* __restrict__ eWih, const float* __restrict__ eWhh,
    const float* __restrict__ dWhh, const float* __restrict__ f1W,
    __hip_bfloat16* __restrict__ wb) {
  for (int i = blockIdx.x * blockDim.x + threadIdx.x; i < W_TOT_;
       i += gridDim.x * blockDim.x) {
    float v;
    if (i < W_EHH_)      v = eWih[i - W_EIH_];
    else if (i < W_DHH_) v = eWhh[i - W_EHH_];
    else if (i < W_F1_)  v = dWhh[i - W_DHH_];
    else                 v = f1W[i - W_F1_];
    wb[i] = __float2bfloat16(v);
  }
}

// ============================ ENCODER ============================
__global__ __launch_bounds__(1024) void af_encoder(
    const float* __restrict__ x,
    const float* __restrict__ h0,
    const float* __restrict__ ebih,
    const float* __restrict__ ebhh,
    const __hip_bfloat16* __restrict__ eWihB,
    const __hip_bfloat16* __restrict__ eWhhB,
    __hip_bfloat16* __restrict__ hs)
{
  __shared__ __hip_bfloat16 sh_h[BTE_ * HSTR_];      // h hi
  __shared__ __hip_bfloat16 sh_l[BTE_ * HSTR_];      // h lo
  __shared__ __hip_bfloat16 sh_x[2][BTE_ * XSTR_];   // x hi (double buffer)
  __shared__ __hip_bfloat16 sh_xl[2][BTE_ * XSTR_];  // x lo
  __shared__ float s_ebr[H_], s_ebz[H_], s_ebin[H_], s_ebhn[H_];

  const int tid  = threadIdx.x;
  const int b0   = blockIdx.x * BTE_;
  const int lane = tid & 63;
  const int wv   = tid >> 6;        // 0..15: wave = column block
  const int quad = lane >> 4;
  const int l16  = lane & 15;
  const int g    = wv * 16 + l16;   // this lane's gate column 0..255
  const int row  = tid >> 6;        // 0..15 (staging row)
  const int col  = tid & 63;        // 0..63 (staging col)

  // prologue
  if (tid < H_) {
    s_ebr[tid]  = ebih[tid]          + ebhh[tid];
    s_ebz[tid]  = ebih[H_ + tid]     + ebhh[H_ + tid];
    s_ebin[tid] = ebih[2 * H_ + tid];
    s_ebhn[tid] = ebhh[2 * H_ + tid];
  }
  {
    const int c4 = col * 4;
    float4 v4 = *(const float4*)(h0 + (size_t)(b0 + row) * H_ + c4);
    float vv[4] = {v4.x, v4.y, v4.z, v4.w};
#pragma unroll
    for (int j = 0; j < 4; ++j) {
      unsigned short hi = f2bf_(vv[j]);
      sh_h[row * HSTR_ + c4 + j] = __float2bfloat16(vv[j]);
      sh_l[row * HSTR_ + c4 + j] = __float2bfloat16(vv[j] - bf2f_(hi));
    }
    float xv = x[((size_t)(b0 + row) * T_) * F_ + col];
    unsigned short xh = f2bf_(xv);
    sh_x[0][row * XSTR_ + col]  = __float2bfloat16(xv);
    sh_xl[0][row * XSTR_ + col] = __float2bfloat16(xv - bf2f_(xh));
  }
  __syncthreads();

  const __hip_bfloat16* pr = eWhhB + (size_t)g * H_ + quad * 8;
  const __hip_bfloat16* pz = eWhhB + (size_t)(H_ + g) * H_ + quad * 8;
  const __hip_bfloat16* pn = eWhhB + (size_t)(2 * H_ + g) * H_ + quad * 8;
  const __hip_bfloat16* qr = eWihB + (size_t)g * F_ + quad * 8;
  const __hip_bfloat16* qz = eWihB + (size_t)(H_ + g) * F_ + quad * 8;
  const __hip_bfloat16* qn = eWihB + (size_t)(2 * H_ + g) * F_ + quad * 8;
  const float br_ = s_ebr[g], bz_ = s_ebz[g], bin_ = s_ebin[g], bhn_ = s_ebhn[g];

  for (int t = 0; t < T_; ++t) {
    const int cur = t & 1, nxt = cur ^ 1;

    // ---- phase 1: preload h fragments (regs) + x(t+1) prefetch into nxt ----
    bf16x8 ah[8], al[8];
#pragma unroll
    for (int kk = 0; kk < 8; ++kk) {
      ah[kk] = *(const bf16x8*)&sh_h[l16 * HSTR_ + kk * 32 + quad * 8];
      al[kk] = *(const bf16x8*)&sh_l[l16 * HSTR_ + kk * 32 + quad * 8];
    }
    if (t + 1 < T_) {
      float xv = x[((size_t)(b0 + row) * T_ + (t + 1)) * F_ + col];
      unsigned short xh = f2bf_(xv);
      sh_x[nxt][row * XSTR_ + col]  = __float2bfloat16(xv);
      sh_xl[nxt][row * XSTR_ + col] = __float2bfloat16(xv - bf2f_(xh));
    }
    __syncthreads();

    // ---- phase 2: MFMA + gate math + in-place h update ----
    f32x4 ar = {0.f, 0.f, 0.f, 0.f}, az = ar, ani = ar, anh = ar;
#pragma unroll
    for (int kk = 0; kk < 8; ++kk) {
      bf16x8 br = *(const bf16x8*)(pr + kk * 32);
      bf16x8 bz = *(const bf16x8*)(pz + kk * 32);
      bf16x8 bn = *(const bf16x8*)(pn + kk * 32);
      ar  = mfma16(al[kk], br, ar);  ar  = mfma16(ah[kk], br, ar);
      az  = mfma16(al[kk], bz, az);  az  = mfma16(ah[kk], bz, az);
      anh = mfma16(al[kk], bn, anh); anh = mfma16(ah[kk], bn, anh);
    }
#pragma unroll
    for (int kk = 0; kk < 2; ++kk) {
      bf16x8 ax  = *(const bf16x8*)&sh_x[cur][l16 * XSTR_ + kk * 32 + quad * 8];
      bf16x8 axl = *(const bf16x8*)&sh_xl[cur][l16 * XSTR_ + kk * 32 + quad * 8];
      bf16x8 br = *(const bf16x8*)(qr + kk * 32);
      bf16x8 bz = *(const bf16x8*)(qz + kk * 32);
      bf16x8 bn = *(const bf16x8*)(qn + kk * 32);
      ar  = mfma16(axl, br, ar);  ar  = mfma16(ax, br, ar);
      az  = mfma16(axl, bz, az);  az  = mfma16(ax, bz, az);
      ani = mfma16(axl, bn, ani); ani = mfma16(ax, bn, ani);
    }
#pragma unroll
    for (int i = 0; i < 4; ++i) {
      const int m = quad * 4 + i;
      float r = sigm_(ar[i] + br_);
      float z = sigm_(az[i] + bz_);
      float n = tanh_(ani[i] + bin_ + r * (anh[i] + bhn_));
      float hold = __bfloat162float(sh_h[m * HSTR_ + g]) +
                   __bfloat162float(sh_l[m * HSTR_ + g]);
      float hn = (1.0f - z) * n + z * hold;
      unsigned short hi = f2bf_(hn);
      sh_h[m * HSTR_ + g] = __float2bfloat16(hn);
      sh_l[m * HSTR_ + g] = __float2bfloat16(hn - bf2f_(hi));
    }
    __syncthreads();

    // ---- phase 3: hs store (nontemporal, bf16 hi, 8B via u64) ----
    {
      const int c4 = col * 4;
      unsigned long long hv = *(const unsigned long long*)&sh_h[row * HSTR_ + c4];
      __builtin_nontemporal_store(
          hv, (unsigned long long*)(hs + ((size_t)(b0 + row) * T_ + t) * H_ + c4));
    }
  }
}

// ============================ DECODER ============================
__global__ __launch_bounds__(512) void af_decoder(
    const float* __restrict__ x,
    const float* __restrict__ dWih,
    const float* __restrict__ dbih,
    const float* __restrict__ dbhh,
    const float* __restrict__ aWq,
    const float* __restrict__ abq,
    const float* __restrict__ f1b,
    const float* __restrict__ f2W,
    const float* __restrict__ f2b,
    const __hip_bfloat16* __restrict__ dWhhB,
    const __hip_bfloat16* __restrict__ f1WB,
    const __hip_bfloat16* __restrict__ hs,
    float* __restrict__ dout)
{
  __shared__ __hip_bfloat16 ctxh[16 * HSTR_], ctxl[16 * HSTR_];  // rows 8..15 zero
  __shared__ __hip_bfloat16 hdh[16 * HSTR_],  hdl[16 * HSTR_];   // rows 8..15 zero
  __shared__ __hip_bfloat16 f1h[BTD_ * HSTR_], f1l[BTD_ * HSTR_];
  __shared__ float s_A[BTD_ * T_], s_C[BTD_ * T_];
  __shared__ float s_w[BTD_ * 132];
  __shared__ float s_dbr[H_], s_dbz[H_], s_dbin[H_], s_dbhn[H_];
  __shared__ float s_dwih[3 * H_];
  __shared__ float s_wq[H_], s_bq[H_], s_f1b[H_], s_f2w[H_];
  __shared__ float s_f2b;
  __shared__ float s_prev[BTD_];

  const int tid  = threadIdx.x;
  const int b0   = blockIdx.x * BTD_;
  const int lane = tid & 63;
  const int wid  = tid >> 6;    // 0..7 : wave id == batch row for 64-lane phases
  const int quad = lane >> 4;
  const int l16  = lane & 15;
  const int mg   = wid;
  const int cg   = lane;

  // prologue: constants + zero pad rows + prev init
  if (tid < H_) {
    s_dbr[tid]  = dbih[tid]          + dbhh[tid];
    s_dbz[tid]  = dbih[H_ + tid]     + dbhh[H_ + tid];
    s_dbin[tid] = dbih[2 * H_ + tid];
    s_dbhn[tid] = dbhh[2 * H_ + tid];
    s_wq[tid]   = aWq[tid];
    s_bq[tid]   = abq[tid];
    s_f1b[tid]  = f1b[tid];
    s_f2w[tid]  = f2W[tid];
  }
  for (int i = tid; i < 3 * H_; i += 512) s_dwih[i] = dWih[i];
  if (tid == 0) s_f2b = f2b[0];
  if (tid < BTD_) s_prev[tid] = x[((size_t)(b0 + tid) * T_ + (T_ - 1)) * F_];
  for (int i = tid; i < 8 * HSTR_; i += 512) {
    ctxh[8 * HSTR_ + i] = __float2bfloat16(0.f);
    ctxl[8 * HSTR_ + i] = __float2bfloat16(0.f);
    hdh[8 * HSTR_ + i]  = __float2bfloat16(0.f);
    hdl[8 * HSTR_ + i]  = __float2bfloat16(0.f);
  }
  __syncthreads();

  // ---- A/C tables via MFMA: per wave = one batch row ----
  {
    const size_t bb = (size_t)(b0 + wid) * T_ * H_;
    bf16x8 bhi[8], blo[8];
#pragma unroll
    for (int kk = 0; kk < 8; ++kk) {
#pragma unroll
      for (int j = 0; j < 8; ++j) {
        const int k = kk * 32 + quad * 8 + j;
        float v = (l16 == 0) ? s_wq[k] : ((l16 == 1) ? s_bq[k] : 0.f);
        unsigned short hi = f2bf_(v);
        bhi[kk][j] = (short)hi;
        blo[kk][j] = (short)f2bf_(v - bf2f_(hi));
      }
    }
#pragma unroll 2
    for (int mt = 0; mt < 8; ++mt) {
      const int t0 = mt * 16;
      f32x4 acc = {0.f, 0.f, 0.f, 0.f};
#pragma unroll
      for (int kk = 0; kk < 8; ++kk) {
        bf16x8 a = *(const bf16x8*)(hs + bb + (size_t)(t0 + l16) * H_ +
                                    kk * 32 + quad * 8);
        acc = mfma16(a, bhi[kk], acc);
        acc = mfma16(a, blo[kk], acc);
      }
      if (l16 == 0) {
#pragma unroll
        for (int i = 0; i < 4; ++i) s_A[wid * T_ + t0 + quad * 4 + i] = acc[i] * 0.0625f;
      } else if (l16 == 1) {
#pragma unroll
        for (int i = 0; i < 4; ++i) s_C[wid * T_ + t0 + quad * 4 + i] = acc[i] * 0.0625f;
      }
    }
  }
  __syncthreads();

  // ---- 32 decoder steps ----
  for (int s = 0; s < OUT_; ++s) {
    // P1: softmax over T (scale folded into A/C)
    {
      const float pv = s_prev[mg];
      float sc0 = pv * s_A[mg * T_ + cg]      + s_C[mg * T_ + cg];
      float sc1 = pv * s_A[mg * T_ + cg + 64] + s_C[mg * T_ + cg + 64];
      float mx = fmaxf(sc0, sc1);
#pragma unroll
      for (int off = 32; off >= 1; off >>= 1) mx = fmaxf(mx, __shfl_xor(mx, off, 64));
      float e0 = __expf(sc0 - mx), e1 = __expf(sc1 - mx);
      float ss = e0 + e1;
#pragma unroll
      for (int off = 32; off >= 1; off >>= 1) ss += __shfl_xor(ss, off, 64);
      const float inv = 1.0f / ss;
      s_w[mg * 132 + cg]      = e0 * inv;
      s_w[mg * 132 + cg + 64] = e1 * inv;
    }
    __syncthreads();

    // P2: ctx = sum_t w[t] * hs[b,t,:]  (each lane: 4 columns)
    {
      const int c4 = cg * 4;
      float a0 = 0.f, a1 = 0.f, a2 = 0.f, a3 = 0.f;
      const __hip_bfloat16* hp = hs + (size_t)(b0 + mg) * T_ * H_ + c4;
      const float* wp = &s_w[mg * 132];
#pragma unroll 8
      for (int t = 0; t < T_; ++t) {
        uint2 hv = *(const uint2*)(hp + (size_t)t * H_);
        const float wt = wp[t];
        a0 = fmaf(wt, __uint_as_float(hv.x << 16),         a0);
        a1 = fmaf(wt, __uint_as_float(hv.x & 0xFFFF0000u), a1);
        a2 = fmaf(wt, __uint_as_float(hv.y << 16),         a2);
        a3 = fmaf(wt, __uint_as_float(hv.y & 0xFFFF0000u), a3);
      }
      float vv[4] = {a0, a1, a2, a3};
#pragma unroll
      for (int j = 0; j < 4; ++j) {
        unsigned short hi = f2bf_(vv[j]);
        ctxh[mg * HSTR_ + c4 + j] = __float2bfloat16(vv[j]);
        ctxl[mg * HSTR_ + c4 + j] = __float2bfloat16(vv[j] - bf2f_(hi));
      }
    }
    __syncthreads();

    // P3: decoder GRU (MFMA on ctx, scalar gi from prev)
    {
      bf16x8 ah[8], al[8];
#pragma unroll
      for (int kk = 0; kk < 8; ++kk) {
        ah[kk] = *(const bf16x8*)&ctxh[l16 * HSTR_ + kk * 32 + quad * 8];
        al[kk] = *(const bf16x8*)&ctxl[l16 * HSTR_ + kk * 32 + quad * 8];
      }
#pragma unroll
      for (int s2 = 0; s2 < 2; ++s2) {
        const int c = 2 * wid + s2;
        const int g = 16 * c + l16;
        const __hip_bfloat16* pr = dWhhB + (size_t)g * H_ + quad * 8;
        const __hip_bfloat16* pz = dWhhB + (size_t)(H_ + g) * H_ + quad * 8;
        const __hip_bfloat16* pn = dWhhB + (size_t)(2 * H_ + g) * H_ + quad * 8;
        f32x4 ar = {0.f, 0.f, 0.f, 0.f}, az = ar, anh = ar;
#pragma unroll
        for (int kk = 0; kk < 8; ++kk) {
          bf16x8 br = *(const bf16x8*)(pr + kk * 32);
          bf16x8 bz = *(const bf16x8*)(pz + kk * 32);
          bf16x8 bn = *(const bf16x8*)(pn + kk * 32);
          ar  = mfma16(al[kk], br, ar);  ar  = mfma16(ah[kk], br, ar);
          az  = mfma16(al[kk], bz, az);  az  = mfma16(ah[kk], bz, az);
          anh = mfma16(al[kk], bn, anh); anh = mfma16(ah[kk], bn, anh);
        }
        const float dr = s_dbr[g], dz = s_dbz[g], din = s_dbin[g], dhn = s_dbhn[g];
        const float wir = s_dwih[g], wiz = s_dwih[H_ + g], win = s_dwih[2 * H_ + g];
#pragma unroll
        for (int i = 0; i < 4; ++i) {
          const int m = quad * 4 + i;
          if (m < BTD_) {
            const float pv = s_prev[m];
            float r = sigm_(ar[i] + pv * wir + dr);
            float z = sigm_(az[i] + pv * wiz + dz);
            float n = tanh_(pv * win + din + r * (anh[i] + dhn));
            float ctxv = __bfloat162float(ctxh[m * HSTR_ + g]) +
                         __bfloat162float(ctxl[m * HSTR_ + g]);
            float hd = (1.0f - z) * n + z * ctxv;
            unsigned short hi = f2bf_(hd);
            hdh[m * HSTR_ + g] = __float2bfloat16(hd);
            hdl[m * HSTR_ + g] = __float2bfloat16(hd - bf2f_(hi));
          }
        }
      }
    }
    __syncthreads();

    // P4: fc1 + relu (MFMA)
    {
      bf16x8 ad[8], adl[8];
#pragma unroll
      for (int kk = 0; kk < 8; ++kk) {
        ad[kk]  = *(const bf16x8*)&hdh[l16 * HSTR_ + kk * 32 + quad * 8];
        adl[kk] = *(const bf16x8*)&hdl[l16 * HSTR_ + kk * 32 + quad * 8];
      }
#pragma unroll
      for (int s2 = 0; s2 < 2; ++s2) {
        const int c = 2 * wid + s2;
        const int j = 16 * c + l16;
        const __hip_bfloat16* pw = f1WB + (size_t)j * H_ + quad * 8;
        f32x4 a1 = {0.f, 0.f, 0.f, 0.f};
#pragma unroll
        for (int kk = 0; kk < 8; ++kk) {
          bf16x8 bw = *(const bf16x8*)(pw + kk * 32);
          a1 = mfma16(adl[kk], bw, a1);
          a1 = mfma16(ad[kk],  bw, a1);
        }
        const float bj = s_f1b[j];
#pragma unroll
        for (int i = 0; i < 4; ++i) {
          const int m = quad * 4 + i;
          if (m < BTD_) {
            float v = fmaxf(a1[i] + bj, 0.0f);
            unsigned short hi = f2bf_(v);
            f1h[m * HSTR_ + j] = __float2bfloat16(v);
            f1l[m * HSTR_ + j] = __float2bfloat16(v - bf2f_(hi));
          }
        }
      }
    }
    __syncthreads();

    // P5: fc2 dot -> out, update prev
    {
      const int j0 = cg * 4;
      float p = 0.f;
#pragma unroll
      for (int j = 0; j < 4; ++j)
        p += (__bfloat162float(f1h[mg * HSTR_ + j0 + j]) +
              __bfloat162float(f1l[mg * HSTR_ + j0 + j])) * s_f2w[j0 + j];
#pragma unroll
      for (int off = 32; off >= 1; off >>= 1) p += __shfl_xor(p, off, 64);
      if (cg == 0) {
        float o = p + s_f2b;
        s_prev[mg] = o;
        dout[(size_t)(b0 + mg) * OUT_ + s] = o;
      }
    }
    __syncthreads();
  }
}

extern "C" void kernel_launch(void* const* d_in, const int* in_sizes, int n_in,
                              void* d_out, int out_size, void* d_ws, size_t ws_size,
                              hipStream_t stream) {
  (void)in_sizes; (void)n_in; (void)out_size; (void)ws_size;
  const float* x    = (const float*)d_in[0];
  const float* h0   = (const float*)d_in[1];
  const float* eWih = (const float*)d_in[2];
  const float* eWhh = (const float*)d_in[3];
  const float* ebih = (const float*)d_in[4];
  const float* ebhh = (const float*)d_in[5];
  const float* dWih = (const float*)d_in[6];
  const float* dWhh = (const float*)d_in[7];
  const float* dbih = (const float*)d_in[8];
  const float* dbhh = (const float*)d_in[9];
  const float* aWq  = (const float*)d_in[10];
  const float* abq  = (const float*)d_in[11];
  const float* f1W  = (const float*)d_in[12];
  const float* f1b  = (const float*)d_in[13];
  const float* f2W  = (const float*)d_in[14];
  const float* f2b  = (const float*)d_in[15];

  __hip_bfloat16* hs = (__hip_bfloat16*)d_ws;  // 134,217,728 B
  __hip_bfloat16* wb = (__hip_bfloat16*)((char*)d_ws + (size_t)B_ * T_ * H_ * 2);

  hipLaunchKernelGGL(af_convert_weights, dim3(256), dim3(256), 0, stream,
                     eWih, eWhh, dWhh, f1W, wb);
  hipLaunchKernelGGL(af_encoder, dim3(NBE_), dim3(1024), 0, stream,
                     x, h0, ebih, ebhh, wb + W_EIH_, wb + W_EHH_, hs);
  hipLaunchKernelGGL(af_decoder, dim3(NBD_), dim3(512), 0, stream,
                     x, dWih, dbih, dbhh, aWq, abq, f1b, f2W, f2b,
                     wb + W_DHH_, wb + W_F1_, hs, (float*)d_out);
}